// Round 18
// baseline (135.620 us; speedup 1.0000x reference)
//
#include <hip/hip_runtime.h>

#define BS 16
#define S  256
#define H  1024
#define T  32
#define IT 16               // i-tile rows per block
#define JT 64               // j-tile rows per block

// ws layout (floats): ps[512]
#define PS_OFF 0

typedef __bf16 bf16x8 __attribute__((ext_vector_type(8)));
typedef float  f32x4  __attribute__((ext_vector_type(4)));

__device__ inline bf16x8 to_bf8(float4 lo, float4 hi) {
    bf16x8 r;
    r[0] = (__bf16)lo.x; r[1] = (__bf16)lo.y; r[2] = (__bf16)lo.z; r[3] = (__bf16)lo.w;
    r[4] = (__bf16)hi.x; r[5] = (__bf16)hi.y; r[6] = (__bf16)hi.z; r[7] = (__bf16)hi.w;
    return r;
}

// ---------------------------------------------------------------------------
// K1: ps[b,t] = seq[b,:] . W[t,2H:3H] + bias[t]  (R10-proven wave-parallel)
// ---------------------------------------------------------------------------
__global__ __launch_bounds__(256) void ps_kernel(
    const float* __restrict__ seq, const float* __restrict__ W,
    const float* __restrict__ bias, float* __restrict__ ws)
{
    const int lane = threadIdx.x & 63, wv = threadIdx.x >> 6;
    float* ps = ws + PS_OFF;
    const int o = blockIdx.x * 4 + wv;                // 0..511
    const int bb = o >> 5, t = o & 31;
    const float4* sp = (const float4*)(seq + (size_t)bb * H) + lane * 4;
    const float4* wp = (const float4*)(W + (size_t)t * (3 * H) + 2 * H) + lane * 4;
    float acc = 0.f;
    #pragma unroll
    for (int k = 0; k < 4; ++k) {
        float4 a = sp[k], w = wp[k];
        acc += a.x * w.x + a.y * w.y + a.z * w.z + a.w * w.w;
    }
    #pragma unroll
    for (int m = 32; m >= 1; m >>= 1) acc += __shfl_xor(acc, m);
    if (lane == 0) ps[o] = acc + bias[t];
}

// ---------------------------------------------------------------------------
// K2: tile-recompute. Block = (b, it, jt): b=blk>>6, it=(blk>>2)&15, jt=blk&3.
//   Independent blocks — NO p1/p2 materialization, no reduce, no dependency.
//   Per block: stage E rows {i0..i0+16, j0..j0+64} as bf16 per k-chunk (42KB),
//   4 waves: wave w computes p2 for j-subtile rows [16w,16w+16) (16 MFMA/chunk)
//   + p1 k-share (k-steps 2w,2w+1; 4 MFMA/chunk). p1 LDS-reduced across waves,
//   + ps -> s1. Then write the block's 16x64x32 output patch (coalesced 1KB).
// ---------------------------------------------------------------------------
__global__ __launch_bounds__(256) void tile_kernel(
    const float* __restrict__ E, const float* __restrict__ W,
    const float* __restrict__ ws, float* __restrict__ out)
{
    __shared__ __align__(16) __bf16 Es[80][264];      // 42.2 KB, reused after k-loop

    const int tid = threadIdx.x;
    const int lane = tid & 63, w = tid >> 6;
    const int blk = blockIdx.x;
    const int b = blk >> 6, it = (blk >> 2) & 15, jt = blk & 3;
    const int i0 = it * IT, j0 = jt * JT;

    const int col  = lane & 15;                       // frag row/col selector
    const int ksub = (lane >> 4) * 8;                 // k sub-offset 0/8/16/24

    f32x4 ap2[2] = {{0.f,0.f,0.f,0.f},{0.f,0.f,0.f,0.f}};
    f32x4 ap1[2] = {{0.f,0.f,0.f,0.f},{0.f,0.f,0.f,0.f}};

    for (int kc = 0; kc < 4; ++kc) {                  // k-chunks of 256
        if (kc) __syncthreads();                      // prior MFMA reads done
        // ---- stage 80 rows x 256 k -> bf16 (rows 0..15 = i-tile, 16..79 = j-tile)
        for (int c = tid; c < 80 * 32; c += 256) {
            int row = c >> 5, ch = c & 31;
            int grow = (row < IT) ? (i0 + row) : (j0 + row - IT);
            const float4* src = (const float4*)(E + ((size_t)(b * S + grow)) * H
                                                + kc * 256 + ch * 8);
            *(bf16x8*)&Es[row][ch * 8] = to_bf8(src[0], src[1]);
        }
        __syncthreads();

        // ---- p2: wave's 16-row j-subtile, 8 k-steps x 2 n-tiles ----
        const __bf16* arow2 = &Es[IT + w * 16 + col][ksub];
        #pragma unroll
        for (int s = 0; s < 8; ++s) {
            bf16x8 a = *(const bf16x8*)(arow2 + s * 32);
            #pragma unroll
            for (int nt = 0; nt < 2; ++nt) {
                const float* wb = W + (size_t)(nt * 16 + col) * (3 * H) + H
                                    + kc * 256 + s * 32 + ksub;
                bf16x8 bf = to_bf8(*(const float4*)wb, *(const float4*)(wb + 4));
                ap2[nt] = __builtin_amdgcn_mfma_f32_16x16x32_bf16(a, bf, ap2[nt], 0, 0, 0);
            }
        }
        // ---- p1 k-share: k-steps 2w, 2w+1 ----
        const __bf16* arow1 = &Es[col][ksub];
        #pragma unroll
        for (int sp = 0; sp < 2; ++sp) {
            const int s = w * 2 + sp;
            bf16x8 a = *(const bf16x8*)(arow1 + s * 32);
            #pragma unroll
            for (int nt = 0; nt < 2; ++nt) {
                const float* wb = W + (size_t)(nt * 16 + col) * (3 * H)
                                    + kc * 256 + s * 32 + ksub;
                bf16x8 bf = to_bf8(*(const float4*)wb, *(const float4*)(wb + 4));
                ap1[nt] = __builtin_amdgcn_mfma_f32_16x16x32_bf16(a, bf, ap1[nt], 0, 0, 0);
            }
        }
    }
    __syncthreads();                                  // Es dead -> reuse as float scratch

    // fl regions (floats): pacc[4][16][32] @0 | p2l[4][16][36] @2048 (pad vs
    // 128B bank wrap) | s1[16][32] @4352
    float* fl = (float*)&Es[0][0];
    const int drow = (lane >> 4) * 4;                 // D layout: col=lane&15,row=drow+r
    #pragma unroll
    for (int nt = 0; nt < 2; ++nt)
        #pragma unroll
        for (int r = 0; r < 4; ++r) {
            fl[w * 512 + (drow + r) * 32 + nt * 16 + col]        = ap1[nt][r];
            fl[2048 + w * 576 + (drow + r) * 36 + nt * 16 + col] = ap2[nt][r];
        }
    __syncthreads();

    const float* psv = ws + PS_OFF + b * T;
    for (int e = tid; e < IT * T; e += 256) {         // s1 = Σw pacc + ps
        int t = e & 31;
        fl[4352 + e] = ((fl[e] + fl[512 + e]) + (fl[1024 + e] + fl[1536 + e])) + psv[t];
    }
    __syncthreads();

    // ---- write 16 x (16 j x 32 t) patch; 1KB contiguous per wave-instr ----
    #pragma unroll
    for (int i = 0; i < IT; ++i) {
        const size_t rb4 = (((size_t)(b * S + i0 + i) * S + j0 + w * 16) * T) >> 2;
        #pragma unroll
        for (int h = 0; h < 2; ++h) {
            const int f = lane + h * 64;              // float4 idx 0..127
            const int jl = f >> 3, t4 = f & 7;
            float4 pv = *(const float4*)&fl[2048 + w * 576 + jl * 36 + t4 * 4];
            float4 sv = *(const float4*)&fl[4352 + i * 32 + t4 * 4];
            float4 r;
            r.x = pv.x + sv.x; r.y = pv.y + sv.y;
            r.z = pv.z + sv.z; r.w = pv.w + sv.w;
            ((float4*)out)[rb4 + f] = r;
        }
    }
}

extern "C" void kernel_launch(void* const* d_in, const int* in_sizes, int n_in,
                              void* d_out, int out_size, void* d_ws, size_t ws_size,
                              hipStream_t stream)
{
    const float* seq  = (const float*)d_in[0];   // (16,1024)
    const float* E    = (const float*)d_in[1];   // (16,256,1024)
    const float* W    = (const float*)d_in[2];   // (32,3072)
    const float* bias = (const float*)d_in[3];   // (32,)
    float* out = (float*)d_out;                  // (16,256,256,32) f32
    float* ws  = (float*)d_ws;                   // 2 KB used (ps only)

    ps_kernel<<<128, 256, 0, stream>>>(seq, W, bias, ws);
    tile_kernel<<<1024, 256, 0, stream>>>(E, W, ws, out);
}